// Round 4
// baseline (563.872 us; speedup 1.0000x reference)
//
#include <hip/hip_runtime.h>

#define TT 2048
#define HH 32
#define BB 512
#define SCL 2.8853900817779268f   // 2*log2(e): tanh(x) = 1 - 2/(2^(SCL*x)+1)

typedef float f32x2 __attribute__((ext_vector_type(2)));
typedef float f32x4 __attribute__((ext_vector_type(4)));

// packed fp32 fma with a wave-uniform (SGPR-pair) multiplicand
#define PKFMAS(acc, wv, hs) asm("v_pk_fma_f32 %0, %1, %2, %0" : "+v"(acc) : "v"(wv), "s"(hs))

__device__ __forceinline__ float tanh2(float s) {
    // s is pre-scaled by SCL: tanh = 1 - 2/(exp2(s)+1)
    float e;
    asm("v_exp_f32 %0, %1" : "=v"(e) : "v"(s));
    float r = __builtin_amdgcn_rcpf(e + 1.0f);
    return fmaf(-2.0f, r, 1.0f);
}

struct Accs { f32x2 A0, A1, C0, C1, C2, C3; };

// per-pair j: broadcast h0[2J],h0[2J+1],h1[2J],h1[2J+1] to SGPRs, 3 pk-FMAs
template<int J>
__device__ __forceinline__ void macJ(int h0i, int h1i,
        const f32x2* w0p, const f32x2* w1p, const f32x2* w2p, Accs& a) {
    if constexpr (J < 16) {
        f32x2 hb0, hb1;
        hb0.x = __int_as_float(__builtin_amdgcn_readlane(h0i, 2 * J));
        hb0.y = __int_as_float(__builtin_amdgcn_readlane(h0i, 2 * J + 1));
        hb1.x = __int_as_float(__builtin_amdgcn_readlane(h1i, 2 * J));
        hb1.y = __int_as_float(__builtin_amdgcn_readlane(h1i, 2 * J + 1));
        if constexpr (J & 1) {
            PKFMAS(a.A1, w0p[J], hb0);
            PKFMAS(a.C1, w1p[J], hb0);
            PKFMAS(a.C3, w2p[J], hb1);
        } else {
            PKFMAS(a.A0, w0p[J], hb0);
            PKFMAS(a.C0, w1p[J], hb0);
            PKFMAS(a.C2, w2p[J], hb1);
        }
        macJ<J + 1>(h0i, h1i, w0p, w1p, w2p, a);
    }
}

__global__ __launch_bounds__(64, 1) void rnn_fused(
    const float* __restrict__ x,      // [B, T, 1]
    const float* __restrict__ hid,    // [2, B, H]
    const float* __restrict__ W_ih0,  // [H, 1]
    const float* __restrict__ W_hh0,  // [H, H]
    const float* __restrict__ b_ih0,  // [H]
    const float* __restrict__ b_hh0,  // [H]
    const float* __restrict__ W_ih1,  // [H, H]
    const float* __restrict__ W_hh1,  // [H, H]
    const float* __restrict__ b_ih1,  // [H]
    const float* __restrict__ b_hh1,  // [H]
    const float* __restrict__ W_fc,   // [1, H]
    const float* __restrict__ b_fc,   // [1]
    float* __restrict__ out)          // [B*T] outs ++ [2*B*H] hidden
{
    const int lane = (int)threadIdx.x;   // 0..63; upper half mirrors lower
    const int half = lane >> 5;
    const int i    = lane & 31;          // hidden unit owned by this lane
    const int b    = (int)blockIdx.x;    // one batch per block/wave

    __shared__ float ring[2][32][33];    // [half-copy][slot=t&31][unit], pad 33

    // --- per-lane weight rows, scaled by SCL (tanh exp2-domain fold) ---
    f32x2 w0p[16], w1p[16], w2p[16];
#pragma unroll
    for (int j = 0; j < 8; ++j) {
        f32x4 a = *(const f32x4*)(W_hh0 + i * HH + 4 * j) * SCL;
        w0p[2 * j]     = __builtin_shufflevector(a, a, 0, 1);
        w0p[2 * j + 1] = __builtin_shufflevector(a, a, 2, 3);
        f32x4 c = *(const f32x4*)(W_ih1 + i * HH + 4 * j) * SCL;
        w1p[2 * j]     = __builtin_shufflevector(c, c, 0, 1);
        w1p[2 * j + 1] = __builtin_shufflevector(c, c, 2, 3);
        f32x4 d = *(const f32x4*)(W_hh1 + i * HH + 4 * j) * SCL;
        w2p[2 * j]     = __builtin_shufflevector(d, d, 0, 1);
        w2p[2 * j + 1] = __builtin_shufflevector(d, d, 2, 3);
    }
    const float wxs    = SCL * W_ih0[i];
    const float bias0s = SCL * (b_ih0[i] + b_hh0[i]);
    const float bias1s = SCL * (b_ih1[i] + b_hh1[i]);
    const float bfc    = b_fc[0];
    float wfv[32];
#pragma unroll
    for (int j = 0; j < 32; ++j) wfv[j] = W_fc[j];

    // --- h state: scalar per lane (unit i), mirrored across halves ---
    float h0n = hid[b * HH + i];              // h0[t-1]
    float h1n = hid[BB * HH + b * HH + i];    // h1[t-2]

    const float* xrow = x + b * TT;
    float* orow = out + b * TT;

    float xcur = xrow[i];        // x for current 32-block (lane i holds x[base+i])
    float xnxt = xrow[32 + i];   // next block, prefetched

    // iter t computes h0[t] and (t>0) h1[t-1]
    for (int tb2 = 0; tb2 < 128; ++tb2) {
        const int koff = (tb2 & 1) << 4;     // position within the 32-block
#pragma unroll
        for (int k = 0; k < 16; ++k) {
            float xv = __int_as_float(
                __builtin_amdgcn_readlane(__float_as_int(xcur), koff + k));

            Accs ac;
            ac.A0 = f32x2{bias0s, 0.f}; ac.A1 = f32x2{0.f, 0.f};
            ac.C0 = f32x2{bias1s, 0.f}; ac.C1 = f32x2{0.f, 0.f};
            ac.C2 = f32x2{0.f, 0.f};    ac.C3 = f32x2{0.f, 0.f};
            macJ<0>(__float_as_int(h0n), __float_as_int(h1n), w0p, w1p, w2p, ac);

            f32x2 As = ac.A0 + ac.A1;
            float nh0 = tanh2(fmaf(wxs, xv, As.x + As.y));

            if (k != 0 || tb2 != 0) {        // layer1 valid for t >= 1
                f32x2 Cs = (ac.C0 + ac.C1) + (ac.C2 + ac.C3);
                float nh1 = tanh2(Cs.x + Cs.y);
                ring[half][(koff + k + 31) & 31][i] = nh1;   // slot (t-1)&31
                h1n = nh1;
            }
            h0n = nh0;

            if (k == 0) {
                if (tb2 != 0 && (tb2 & 1) == 0) {
                    // flush out[base-32 .. base-1], base = tb2*16; lane r -> out[base-32+r]
                    float f0 = bfc, f1 = 0.f, f2 = 0.f, f3 = 0.f;
                    const float* rr = &ring[half][i][0];
#pragma unroll
                    for (int j = 0; j < 32; j += 4) {
                        f0 = fmaf(wfv[j],     rr[j],     f0);
                        f1 = fmaf(wfv[j + 1], rr[j + 1], f1);
                        f2 = fmaf(wfv[j + 2], rr[j + 2], f2);
                        f3 = fmaf(wfv[j + 3], rr[j + 3], f3);
                    }
                    if (lane < 32) orow[tb2 * 16 - 32 + i] = (f0 + f1) + (f2 + f3);
                }
            }
            if (k == 15 && (tb2 & 1)) {
                // end of a 32-block: rotate x window, prefetch block m+2
                xcur = xnxt;
                int idx = tb2 * 16 + 48 + i;
                if (idx >= TT) idx = TT - 1;
                xnxt = xrow[idx];
            }
        }
    }

    // ---- epilogue t = TT: h1[TT-1] + final flush ----
    {
        Accs ac;
        ac.A0 = f32x2{bias0s, 0.f}; ac.A1 = f32x2{0.f, 0.f};
        ac.C0 = f32x2{bias1s, 0.f}; ac.C1 = f32x2{0.f, 0.f};
        ac.C2 = f32x2{0.f, 0.f};    ac.C3 = f32x2{0.f, 0.f};
        macJ<0>(__float_as_int(h0n), __float_as_int(h1n), w0p, w1p, w2p, ac);
        f32x2 Cs = (ac.C0 + ac.C1) + (ac.C2 + ac.C3);
        float nh1 = tanh2(Cs.x + Cs.y);
        ring[half][31][i] = nh1;     // slot (TT-1)&31 = 31
        h1n = nh1;

        float f0 = bfc, f1 = 0.f, f2 = 0.f, f3 = 0.f;
        const float* rr = &ring[half][i][0];
#pragma unroll
        for (int j = 0; j < 32; j += 4) {
            f0 = fmaf(wfv[j],     rr[j],     f0);
            f1 = fmaf(wfv[j + 1], rr[j + 1], f1);
            f2 = fmaf(wfv[j + 2], rr[j + 2], f2);
            f3 = fmaf(wfv[j + 3], rr[j + 3], f3);
        }
        if (lane < 32) orow[TT - 32 + i] = (f0 + f1) + (f2 + f3);
    }

    // final hidden [2, B, H]
    if (lane < 32) {
        out[BB * TT + b * HH + i]           = h0n;
        out[BB * TT + BB * HH + b * HH + i] = h1n;
    }
}

extern "C" void kernel_launch(void* const* d_in, const int* in_sizes, int n_in,
                              void* d_out, int out_size, void* d_ws, size_t ws_size,
                              hipStream_t stream) {
    const float* xp    = (const float*)d_in[0];
    const float* hid   = (const float*)d_in[1];
    const float* Wih0  = (const float*)d_in[2];
    const float* Whh0  = (const float*)d_in[3];
    const float* bih0  = (const float*)d_in[4];
    const float* bhh0  = (const float*)d_in[5];
    const float* Wih1  = (const float*)d_in[6];
    const float* Whh1  = (const float*)d_in[7];
    const float* bih1  = (const float*)d_in[8];
    const float* bhh1  = (const float*)d_in[9];
    const float* Wfc   = (const float*)d_in[10];
    const float* bfc   = (const float*)d_in[11];
    float* outp        = (float*)d_out;

    rnn_fused<<<BB, 64, 0, stream>>>(xp, hid, Wih0, Whh0, bih0, bhh0,
                                     Wih1, Whh1, bih1, bhh1, Wfc, bfc, outp);
}